// Round 1
// baseline (1147.933 us; speedup 1.0000x reference)
//
#include <hip/hip_runtime.h>
#include <hip/hip_bf16.h>

#define BN_EPS 1e-5f

// ---------------- degree histogram ----------------
__global__ void hist_kernel(const int* __restrict__ dst, int* __restrict__ cnt, int e) {
    int i = blockIdx.x * 256 + threadIdx.x;
    if (i < e) atomicAdd(&cnt[dst[i]], 1);
}

__global__ void dinv_kernel(const int* __restrict__ cnt, float* __restrict__ dinv, int n) {
    int i = blockIdx.x * 256 + threadIdx.x;
    if (i < n) dinv[i] = rsqrtf((float)(cnt[i] + 1));   // deg = indeg + self-loop >= 1
}

// ---------------- exclusive scan (3-pass, chunk = 1024) ----------------
#define SCAN_CHUNK 1024

__global__ void scan_block_sums(const int* __restrict__ cnt, int* __restrict__ bsums, int n) {
    __shared__ int sdata[256];
    int b = blockIdx.x, t = threadIdx.x;
    int base = b * SCAN_CHUNK;
    int s = 0;
    for (int i = t; i < SCAN_CHUNK; i += 256) {
        int idx = base + i;
        if (idx < n) s += cnt[idx];
    }
    sdata[t] = s;
    __syncthreads();
    for (int off = 128; off > 0; off >>= 1) {
        if (t < off) sdata[t] += sdata[t + off];
        __syncthreads();
    }
    if (t == 0) bsums[b] = sdata[0];
}

__global__ void scan_exclusive_bsums(int* __restrict__ bsums, int nb) {
    if (threadIdx.x == 0 && blockIdx.x == 0) {
        int acc = 0;
        for (int i = 0; i < nb; i++) { int v = bsums[i]; bsums[i] = acc; acc += v; }
    }
}

__global__ void scan_write(const int* __restrict__ cnt, const int* __restrict__ bsums,
                           int* __restrict__ row_start, int n, int e_total) {
    __shared__ int sdata[256];
    int b = blockIdx.x, t = threadIdx.x;
    int base = b * SCAN_CHUNK + t * 4;
    int v0 = 0, v1 = 0, v2 = 0, v3 = 0;
    if (base + 0 < n) v0 = cnt[base + 0];
    if (base + 1 < n) v1 = cnt[base + 1];
    if (base + 2 < n) v2 = cnt[base + 2];
    if (base + 3 < n) v3 = cnt[base + 3];
    int tsum = v0 + v1 + v2 + v3;
    sdata[t] = tsum;
    __syncthreads();
    for (int off = 1; off < 256; off <<= 1) {       // inclusive Hillis-Steele
        int x = (t >= off) ? sdata[t - off] : 0;
        __syncthreads();
        sdata[t] += x;
        __syncthreads();
    }
    int excl = sdata[t] - tsum + bsums[b];
    if (base + 0 < n) row_start[base + 0] = excl;
    if (base + 1 < n) row_start[base + 1] = excl + v0;
    if (base + 2 < n) row_start[base + 2] = excl + v0 + v1;
    if (base + 3 < n) row_start[base + 3] = excl + v0 + v1 + v2;
    if (b == 0 && t == 0) row_start[n] = e_total;
}

// ---------------- CSR scatter ----------------
__global__ void scatter_kernel(const int* __restrict__ src, const int* __restrict__ dst,
                               const int* __restrict__ row_start, int* __restrict__ cursor,
                               const float* __restrict__ dinv,
                               int* __restrict__ csr_src, float* __restrict__ csr_val, int e) {
    int i = blockIdx.x * 256 + threadIdx.x;
    if (i >= e) return;
    int s = src[i], d = dst[i];
    int pos = row_start[d] + atomicAdd(&cursor[d], 1);
    csr_src[pos] = s;
    csr_val[pos] = dinv[s] * dinv[d];
}

// ---------------- dense linear: out[N,64] = in[N,K] @ w[K,64] ----------------
// block = 256 threads = 4 rows x 64 features; w staged in LDS
__global__ void lin_kernel(const float* __restrict__ in, const float* __restrict__ w,
                           float* __restrict__ out, int n, int K) {
    __shared__ float wl[128 * 64];
    int t = threadIdx.x;
    for (int idx = t; idx < K * 64; idx += 256) wl[idx] = w[idx];
    __syncthreads();
    int f = t & 63;
    int r = blockIdx.x * 4 + (t >> 6);
    if (r >= n) return;
    const float* xr = in + (size_t)r * K;
    float acc = 0.f;
#pragma unroll 8
    for (int k = 0; k < K; k++) acc += xr[k] * wl[k * 64 + f];
    out[(size_t)r * 64 + f] = acc;
}

// ---------------- aggregation + bias + BN + ReLU ----------------
// one wave (64 lanes = 64 features) per node
__global__ void agg_kernel(const float* __restrict__ hlin, const int* __restrict__ row_start,
                           const int* __restrict__ csr_src, const float* __restrict__ csr_val,
                           const float* __restrict__ dinv,
                           const float* __restrict__ bias, const float* __restrict__ gam,
                           const float* __restrict__ bet, const float* __restrict__ mu,
                           const float* __restrict__ var,
                           float* __restrict__ out, int n) {
    int wave = blockIdx.x * 4 + (threadIdx.x >> 6);
    int lane = threadIdx.x & 63;
    if (wave >= n) return;
    int i = wave;
    float di = dinv[i];
    float acc = di * di * hlin[(size_t)i * 64 + lane];   // self-loop
    int rs = row_start[i], re = row_start[i + 1];
    for (int j = rs; j < re; j++) {
        int s = csr_src[j];
        float w = csr_val[j];
        acc += w * hlin[(size_t)s * 64 + lane];
    }
    float scale = gam[lane] * rsqrtf(var[lane] + BN_EPS);
    float r = (acc + bias[lane] - mu[lane]) * scale + bet[lane];
    out[(size_t)i * 64 + lane] = r > 0.f ? r : 0.f;
}

// ---------------- pool (sorted batch) + MLP ----------------
// one block (64 threads) per graph
__global__ void pool_mlp_kernel(const float* __restrict__ h, const int* __restrict__ batch,
                                const float* __restrict__ l1w, const float* __restrict__ l1b,
                                const float* __restrict__ l2w, const float* __restrict__ l2b,
                                float* __restrict__ out, int n) {
    int g = blockIdx.x;
    int lane = threadIdx.x;
    // lower_bound(batch, g)
    int lo = 0, hi = n;
    while (lo < hi) { int mid = (lo + hi) >> 1; if (batch[mid] < g) lo = mid + 1; else hi = mid; }
    int start = lo;
    lo = start; hi = n;
    while (lo < hi) { int mid = (lo + hi) >> 1; if (batch[mid] < g + 1) lo = mid + 1; else hi = mid; }
    int end = lo;

    float acc = 0.f;
    for (int i = start; i < end; i++) acc += h[(size_t)i * 64 + lane];

    __shared__ float p[64];
    __shared__ float h1[32];
    p[lane] = acc;
    __syncthreads();
    if (lane < 32) {
        float a = l1b[lane];
#pragma unroll 8
        for (int k = 0; k < 64; k++) a += p[k] * l1w[k * 32 + lane];
        h1[lane] = a > 0.f ? a : 0.f;
    }
    __syncthreads();
    if (lane < 2) {
        float a = l2b[lane];
#pragma unroll 8
        for (int j = 0; j < 32; j++) a += h1[j] * l2w[j * 2 + lane];
        out[g * 2 + lane] = a;
    }
}

extern "C" void kernel_launch(void* const* d_in, const int* in_sizes, int n_in,
                              void* d_out, int out_size, void* d_ws, size_t ws_size,
                              hipStream_t stream) {
    const float* x     = (const float*)d_in[0];
    const int*   ei    = (const int*)d_in[1];
    const int*   batch = (const int*)d_in[2];
    const float* w0 = (const float*)d_in[3];
    const float* b0 = (const float*)d_in[4];
    const float* w1 = (const float*)d_in[5];
    const float* b1 = (const float*)d_in[6];
    const float* w2 = (const float*)d_in[7];
    const float* b2 = (const float*)d_in[8];
    const float* g0 = (const float*)d_in[9];
    const float* be0 = (const float*)d_in[10];
    const float* m0 = (const float*)d_in[11];
    const float* v0 = (const float*)d_in[12];
    const float* g1 = (const float*)d_in[13];
    const float* be1 = (const float*)d_in[14];
    const float* m1 = (const float*)d_in[15];
    const float* v1 = (const float*)d_in[16];
    const float* g2 = (const float*)d_in[17];
    const float* be2 = (const float*)d_in[18];
    const float* m2 = (const float*)d_in[19];
    const float* v2 = (const float*)d_in[20];
    const float* l1w = (const float*)d_in[21];
    const float* l1b = (const float*)d_in[22];
    const float* l2w = (const float*)d_in[23];
    const float* l2b = (const float*)d_in[24];
    float* out = (float*)d_out;

    const int N = in_sizes[2];
    const int E = in_sizes[1] / 2;
    const int F_IN = in_sizes[0] / N;
    const int G = out_size / 2;

    const int* src = ei;
    const int* dst = ei + E;

    // workspace layout
    char* p = (char*)d_ws;
    auto alloc = [&](size_t bytes) -> void* {
        void* r = (void*)p;
        p += (bytes + 255) & ~(size_t)255;
        return r;
    };
    float* dinvp    = (float*)alloc((size_t)N * 4);
    int*   cnt      = (int*)alloc((size_t)N * 4);
    int*   row_start= (int*)alloc((size_t)(N + 1) * 4);
    int*   cursor   = (int*)alloc((size_t)N * 4);
    int    NB       = (N + SCAN_CHUNK - 1) / SCAN_CHUNK;
    int*   bsums    = (int*)alloc((size_t)NB * 4);
    int*   csr_src  = (int*)alloc((size_t)E * 4);
    float* csr_val  = (float*)alloc((size_t)E * 4);
    float* h_a      = (float*)alloc((size_t)N * 64 * 4);
    float* h_b      = (float*)alloc((size_t)N * 64 * 4);
    (void)ws_size;

    // ---- graph preprocessing ----
    hipMemsetAsync(cnt, 0, (size_t)N * 4, stream);
    hist_kernel<<<(E + 255) / 256, 256, 0, stream>>>(dst, cnt, E);
    dinv_kernel<<<(N + 255) / 256, 256, 0, stream>>>(cnt, dinvp, N);
    scan_block_sums<<<NB, 256, 0, stream>>>(cnt, bsums, N);
    scan_exclusive_bsums<<<1, 64, 0, stream>>>(bsums, NB);
    scan_write<<<NB, 256, 0, stream>>>(cnt, bsums, row_start, N, E);
    hipMemsetAsync(cursor, 0, (size_t)N * 4, stream);
    scatter_kernel<<<(E + 255) / 256, 256, 0, stream>>>(src, dst, row_start, cursor, dinvp,
                                                        csr_src, csr_val, E);

    const int nblk = (N + 3) / 4;
    // ---- layer 0 ----
    lin_kernel<<<nblk, 256, 0, stream>>>(x, w0, h_a, N, F_IN);
    agg_kernel<<<nblk, 256, 0, stream>>>(h_a, row_start, csr_src, csr_val, dinvp,
                                         b0, g0, be0, m0, v0, h_b, N);
    // ---- layer 1 ----
    lin_kernel<<<nblk, 256, 0, stream>>>(h_b, w1, h_a, N, 64);
    agg_kernel<<<nblk, 256, 0, stream>>>(h_a, row_start, csr_src, csr_val, dinvp,
                                         b1, g1, be1, m1, v1, h_b, N);
    // ---- layer 2 ----
    lin_kernel<<<nblk, 256, 0, stream>>>(h_b, w2, h_a, N, 64);
    agg_kernel<<<nblk, 256, 0, stream>>>(h_a, row_start, csr_src, csr_val, dinvp,
                                         b2, g2, be2, m2, v2, h_b, N);
    // ---- pool + MLP ----
    pool_mlp_kernel<<<G, 64, 0, stream>>>(h_b, batch, l1w, l1b, l2w, l2b, out, N);
}

// Round 2
// 913.559 us; speedup vs baseline: 1.2565x; 1.2565x over previous
//
#include <hip/hip_runtime.h>
#include <hip/hip_bf16.h>

#define BN_EPS 1e-5f

// ---------------- degree histogram ----------------
__global__ void hist_kernel(const int* __restrict__ dst, int* __restrict__ cnt, int e) {
    int i = blockIdx.x * 256 + threadIdx.x;
    if (i < e) atomicAdd(&cnt[dst[i]], 1);
}

__global__ void dinv_kernel(const int* __restrict__ cnt, float* __restrict__ dinv, int n) {
    int i = blockIdx.x * 256 + threadIdx.x;
    if (i < n) dinv[i] = rsqrtf((float)(cnt[i] + 1));   // deg = indeg + self-loop >= 1
}

// ---------------- exclusive scan (3-pass, chunk = 1024) ----------------
#define SCAN_CHUNK 1024

__global__ void scan_block_sums(const int* __restrict__ cnt, int* __restrict__ bsums, int n) {
    __shared__ int sdata[256];
    int b = blockIdx.x, t = threadIdx.x;
    int base = b * SCAN_CHUNK;
    int s = 0;
    for (int i = t; i < SCAN_CHUNK; i += 256) {
        int idx = base + i;
        if (idx < n) s += cnt[idx];
    }
    sdata[t] = s;
    __syncthreads();
    for (int off = 128; off > 0; off >>= 1) {
        if (t < off) sdata[t] += sdata[t + off];
        __syncthreads();
    }
    if (t == 0) bsums[b] = sdata[0];
}

__global__ void scan_exclusive_bsums(int* __restrict__ bsums, int nb) {
    if (threadIdx.x == 0 && blockIdx.x == 0) {
        int acc = 0;
        for (int i = 0; i < nb; i++) { int v = bsums[i]; bsums[i] = acc; acc += v; }
    }
}

__global__ void scan_write(const int* __restrict__ cnt, const int* __restrict__ bsums,
                           int* __restrict__ row_start, int n, int e_total) {
    __shared__ int sdata[256];
    int b = blockIdx.x, t = threadIdx.x;
    int base = b * SCAN_CHUNK + t * 4;
    int v0 = 0, v1 = 0, v2 = 0, v3 = 0;
    if (base + 0 < n) v0 = cnt[base + 0];
    if (base + 1 < n) v1 = cnt[base + 1];
    if (base + 2 < n) v2 = cnt[base + 2];
    if (base + 3 < n) v3 = cnt[base + 3];
    int tsum = v0 + v1 + v2 + v3;
    sdata[t] = tsum;
    __syncthreads();
    for (int off = 1; off < 256; off <<= 1) {       // inclusive Hillis-Steele
        int x = (t >= off) ? sdata[t - off] : 0;
        __syncthreads();
        sdata[t] += x;
        __syncthreads();
    }
    int excl = sdata[t] - tsum + bsums[b];
    if (base + 0 < n) row_start[base + 0] = excl;
    if (base + 1 < n) row_start[base + 1] = excl + v0;
    if (base + 2 < n) row_start[base + 2] = excl + v0 + v1;
    if (base + 3 < n) row_start[base + 3] = excl + v0 + v1 + v2;
    if (b == 0 && t == 0) row_start[n] = e_total;
}

// ---------------- CSR scatter (packed {src, val}) ----------------
__global__ void scatter_kernel(const int* __restrict__ src, const int* __restrict__ dst,
                               const int* __restrict__ row_start, int* __restrict__ cursor,
                               const float* __restrict__ dinv,
                               int2* __restrict__ csr, int e) {
    int i = blockIdx.x * 256 + threadIdx.x;
    if (i >= e) return;
    int s = src[i], d = dst[i];
    int pos = row_start[d] + atomicAdd(&cursor[d], 1);
    csr[pos] = make_int2(s, __float_as_int(dinv[s] * dinv[d]));
}

// ---------------- dense linear: out[N,64] = in[N,K] @ w[K,64] ----------------
// one wave per row-stream; lane f holds w[:,f] in registers; x-row via
// broadcast float4 loads (same addr across wave -> 1 transaction).
template<int K>
__global__ __launch_bounds__(256) void lin_tpl(const float* __restrict__ in,
                                               const float* __restrict__ w,
                                               float* __restrict__ out, int n) {
    int lane = threadIdx.x & 63;
    int wid = blockIdx.x * 4 + (threadIdx.x >> 6);
    int nw = gridDim.x * 4;
    float wcol[K];
#pragma unroll
    for (int k = 0; k < K; k++) wcol[k] = w[k * 64 + lane];
    for (int r = wid; r < n; r += nw) {
        const float4* xr = (const float4*)(in + (size_t)r * K);
        float acc = 0.f;
#pragma unroll
        for (int k4 = 0; k4 < K / 4; k4++) {
            float4 xv = xr[k4];
            acc += xv.x * wcol[4 * k4 + 0] + xv.y * wcol[4 * k4 + 1]
                 + xv.z * wcol[4 * k4 + 2] + xv.w * wcol[4 * k4 + 3];
        }
        out[(size_t)r * 64 + lane] = acc;
    }
}

// ---------------- aggregation + bias + BN + ReLU ----------------
// one wave (64 lanes = 64 features) per node; edge loop unrolled x4
__global__ __launch_bounds__(256) void agg_kernel(
        const float* __restrict__ hlin, const int* __restrict__ row_start,
        const int2* __restrict__ csr, const float* __restrict__ dinv,
        const float* __restrict__ bias, const float* __restrict__ gam,
        const float* __restrict__ bet, const float* __restrict__ mu,
        const float* __restrict__ var,
        float* __restrict__ out, int n) {
    int i = blockIdx.x * 4 + (threadIdx.x >> 6);
    int lane = threadIdx.x & 63;
    if (i >= n) return;
    float di = dinv[i];
    float acc = di * di * hlin[(size_t)i * 64 + lane];   // self-loop
    int rs = row_start[i], re = row_start[i + 1];
    int j = rs;
    for (; j + 4 <= re; j += 4) {
        int2 e0 = csr[j + 0];
        int2 e1 = csr[j + 1];
        int2 e2 = csr[j + 2];
        int2 e3 = csr[j + 3];
        float h0 = hlin[(size_t)e0.x * 64 + lane];
        float h1 = hlin[(size_t)e1.x * 64 + lane];
        float h2 = hlin[(size_t)e2.x * 64 + lane];
        float h3 = hlin[(size_t)e3.x * 64 + lane];
        acc += __int_as_float(e0.y) * h0;
        acc += __int_as_float(e1.y) * h1;
        acc += __int_as_float(e2.y) * h2;
        acc += __int_as_float(e3.y) * h3;
    }
    for (; j < re; j++) {
        int2 e = csr[j];
        acc += __int_as_float(e.y) * hlin[(size_t)e.x * 64 + lane];
    }
    float scale = gam[lane] * rsqrtf(var[lane] + BN_EPS);
    float r = (acc + bias[lane] - mu[lane]) * scale + bet[lane];
    out[(size_t)i * 64 + lane] = r > 0.f ? r : 0.f;
}

// ---------------- pool (sorted batch) + MLP ----------------
// one block (64 threads) per graph
__global__ void pool_mlp_kernel(const float* __restrict__ h, const int* __restrict__ batch,
                                const float* __restrict__ l1w, const float* __restrict__ l1b,
                                const float* __restrict__ l2w, const float* __restrict__ l2b,
                                float* __restrict__ out, int n) {
    int g = blockIdx.x;
    int lane = threadIdx.x;
    int lo = 0, hi = n;
    while (lo < hi) { int mid = (lo + hi) >> 1; if (batch[mid] < g) lo = mid + 1; else hi = mid; }
    int start = lo;
    lo = start; hi = n;
    while (lo < hi) { int mid = (lo + hi) >> 1; if (batch[mid] < g + 1) lo = mid + 1; else hi = mid; }
    int end = lo;

    float acc = 0.f;
    for (int i = start; i < end; i++) acc += h[(size_t)i * 64 + lane];

    __shared__ float p[64];
    __shared__ float h1[32];
    p[lane] = acc;
    __syncthreads();
    if (lane < 32) {
        float a = l1b[lane];
#pragma unroll 8
        for (int k = 0; k < 64; k++) a += p[k] * l1w[k * 32 + lane];
        h1[lane] = a > 0.f ? a : 0.f;
    }
    __syncthreads();
    if (lane < 2) {
        float a = l2b[lane];
#pragma unroll 8
        for (int j = 0; j < 32; j++) a += h1[j] * l2w[j * 2 + lane];
        out[g * 2 + lane] = a;
    }
}

extern "C" void kernel_launch(void* const* d_in, const int* in_sizes, int n_in,
                              void* d_out, int out_size, void* d_ws, size_t ws_size,
                              hipStream_t stream) {
    const float* x     = (const float*)d_in[0];
    const int*   ei    = (const int*)d_in[1];
    const int*   batch = (const int*)d_in[2];
    const float* w0 = (const float*)d_in[3];
    const float* b0 = (const float*)d_in[4];
    const float* w1 = (const float*)d_in[5];
    const float* b1 = (const float*)d_in[6];
    const float* w2 = (const float*)d_in[7];
    const float* b2 = (const float*)d_in[8];
    const float* g0 = (const float*)d_in[9];
    const float* be0 = (const float*)d_in[10];
    const float* m0 = (const float*)d_in[11];
    const float* v0 = (const float*)d_in[12];
    const float* g1 = (const float*)d_in[13];
    const float* be1 = (const float*)d_in[14];
    const float* m1 = (const float*)d_in[15];
    const float* v1 = (const float*)d_in[16];
    const float* g2 = (const float*)d_in[17];
    const float* be2 = (const float*)d_in[18];
    const float* m2 = (const float*)d_in[19];
    const float* v2 = (const float*)d_in[20];
    const float* l1w = (const float*)d_in[21];
    const float* l1b = (const float*)d_in[22];
    const float* l2w = (const float*)d_in[23];
    const float* l2b = (const float*)d_in[24];
    float* out = (float*)d_out;

    const int N = in_sizes[2];
    const int E = in_sizes[1] / 2;
    const int G = out_size / 2;

    const int* src = ei;
    const int* dst = ei + E;

    // workspace layout
    char* p = (char*)d_ws;
    auto alloc = [&](size_t bytes) -> void* {
        void* r = (void*)p;
        p += (bytes + 255) & ~(size_t)255;
        return r;
    };
    float* dinvp    = (float*)alloc((size_t)N * 4);
    int*   cnt      = (int*)alloc((size_t)N * 4);
    int*   row_start= (int*)alloc((size_t)(N + 1) * 4);
    int*   cursor   = (int*)alloc((size_t)N * 4);
    int    NB       = (N + SCAN_CHUNK - 1) / SCAN_CHUNK;
    int*   bsums    = (int*)alloc((size_t)NB * 4);
    int2*  csr      = (int2*)alloc((size_t)E * 8);
    float* h_a      = (float*)alloc((size_t)N * 64 * 4);
    float* h_b      = (float*)alloc((size_t)N * 64 * 4);
    (void)ws_size;

    // ---- graph preprocessing ----
    hipMemsetAsync(cnt, 0, (size_t)N * 4, stream);
    hist_kernel<<<(E + 255) / 256, 256, 0, stream>>>(dst, cnt, E);
    dinv_kernel<<<(N + 255) / 256, 256, 0, stream>>>(cnt, dinvp, N);
    scan_block_sums<<<NB, 256, 0, stream>>>(cnt, bsums, N);
    scan_exclusive_bsums<<<1, 64, 0, stream>>>(bsums, NB);
    scan_write<<<NB, 256, 0, stream>>>(cnt, bsums, row_start, N, E);
    hipMemsetAsync(cursor, 0, (size_t)N * 4, stream);
    scatter_kernel<<<(E + 255) / 256, 256, 0, stream>>>(src, dst, row_start, cursor, dinvp,
                                                        csr, E);

    const int nblk = (N + 3) / 4;
    const int lgrid = 1024;
    // ---- layer 0 ----
    lin_tpl<128><<<lgrid, 256, 0, stream>>>(x, w0, h_a, N);
    agg_kernel<<<nblk, 256, 0, stream>>>(h_a, row_start, csr, dinvp,
                                         b0, g0, be0, m0, v0, h_b, N);
    // ---- layer 1 ----
    lin_tpl<64><<<lgrid, 256, 0, stream>>>(h_b, w1, h_a, N);
    agg_kernel<<<nblk, 256, 0, stream>>>(h_a, row_start, csr, dinvp,
                                         b1, g1, be1, m1, v1, h_b, N);
    // ---- layer 2 ----
    lin_tpl<64><<<lgrid, 256, 0, stream>>>(h_b, w2, h_a, N);
    agg_kernel<<<nblk, 256, 0, stream>>>(h_a, row_start, csr, dinvp,
                                         b2, g2, be2, m2, v2, h_b, N);
    // ---- pool + MLP ----
    pool_mlp_kernel<<<G, 64, 0, stream>>>(h_b, batch, l1w, l1b, l2w, l2b, out, N);
}

// Round 3
// 691.698 us; speedup vs baseline: 1.6596x; 1.3207x over previous
//
#include <hip/hip_runtime.h>
#include <hip/hip_bf16.h>

#define BN_EPS 1e-5f

// ---------------- degree histogram ----------------
__global__ void hist_kernel(const int* __restrict__ dst, int* __restrict__ cnt, int e) {
    int i = blockIdx.x * 256 + threadIdx.x;
    if (i < e) atomicAdd(&cnt[dst[i]], 1);
}

__global__ void dinv_kernel(const int* __restrict__ cnt, float* __restrict__ dinv, int n) {
    int i = blockIdx.x * 256 + threadIdx.x;
    if (i < n) dinv[i] = rsqrtf((float)(cnt[i] + 1));   // deg = indeg + self-loop >= 1
}

// ---------------- exclusive scan (3-pass, chunk = 1024) ----------------
#define SCAN_CHUNK 1024

__global__ void scan_block_sums(const int* __restrict__ cnt, int* __restrict__ bsums, int n) {
    __shared__ int sdata[256];
    int b = blockIdx.x, t = threadIdx.x;
    int base = b * SCAN_CHUNK;
    int s = 0;
    for (int i = t; i < SCAN_CHUNK; i += 256) {
        int idx = base + i;
        if (idx < n) s += cnt[idx];
    }
    sdata[t] = s;
    __syncthreads();
    for (int off = 128; off > 0; off >>= 1) {
        if (t < off) sdata[t] += sdata[t + off];
        __syncthreads();
    }
    if (t == 0) bsums[b] = sdata[0];
}

__global__ void scan_exclusive_bsums(int* __restrict__ bsums, int nb) {
    if (threadIdx.x == 0 && blockIdx.x == 0) {
        int acc = 0;
        for (int i = 0; i < nb; i++) { int v = bsums[i]; bsums[i] = acc; acc += v; }
    }
}

__global__ void scan_write(const int* __restrict__ cnt, const int* __restrict__ bsums,
                           int* __restrict__ row_start, int n, int e_total) {
    __shared__ int sdata[256];
    int b = blockIdx.x, t = threadIdx.x;
    int base = b * SCAN_CHUNK + t * 4;
    int v0 = 0, v1 = 0, v2 = 0, v3 = 0;
    if (base + 0 < n) v0 = cnt[base + 0];
    if (base + 1 < n) v1 = cnt[base + 1];
    if (base + 2 < n) v2 = cnt[base + 2];
    if (base + 3 < n) v3 = cnt[base + 3];
    int tsum = v0 + v1 + v2 + v3;
    sdata[t] = tsum;
    __syncthreads();
    for (int off = 1; off < 256; off <<= 1) {       // inclusive Hillis-Steele
        int x = (t >= off) ? sdata[t - off] : 0;
        __syncthreads();
        sdata[t] += x;
        __syncthreads();
    }
    int excl = sdata[t] - tsum + bsums[b];
    if (base + 0 < n) row_start[base + 0] = excl;
    if (base + 1 < n) row_start[base + 1] = excl + v0;
    if (base + 2 < n) row_start[base + 2] = excl + v0 + v1;
    if (base + 3 < n) row_start[base + 3] = excl + v0 + v1 + v2;
    if (b == 0 && t == 0) row_start[n] = e_total;
}

// ---------------- CSR scatter (packed {src, val}) ----------------
__global__ void scatter_kernel(const int* __restrict__ src, const int* __restrict__ dst,
                               const int* __restrict__ row_start, int* __restrict__ cursor,
                               const float* __restrict__ dinv,
                               int2* __restrict__ csr, int e) {
    int i = blockIdx.x * 256 + threadIdx.x;
    if (i >= e) return;
    int s = src[i], d = dst[i];
    int pos = row_start[d] + atomicAdd(&cursor[d], 1);
    csr[pos] = make_int2(s, __float_as_int(dinv[s] * dinv[d]));
}

// ---------------- dense linear: out[N,64] = in[N,K] @ w[K,64] ----------------
// block = 256 thr, 64-row tile; x-tile + w staged in LDS (coalesced float4);
// each thread owns a 4x4 micro-tile (rows rg*4.., cols cg*4..): 64 FMA per
// 8 ds_read_b128 -> VALU-bound.
template<int K>
__global__ __launch_bounds__(256) void lin2(const float* __restrict__ in,
                                            const float* __restrict__ w,
                                            float* __restrict__ out, int n) {
    constexpr int XSS = K + 4;                  // +4 pad: breaks pow2 bank stride
    __shared__ float xs[64 * XSS];
    __shared__ float ws[K * 64];
    int t = threadIdx.x;
    int row0 = blockIdx.x * 64;
    int nrows = n - row0; if (nrows > 64) nrows = 64;

    {   // stage w (K*16 float4, contiguous)
        const float4* w4 = (const float4*)w;
        float4* ws4 = (float4*)ws;
#pragma unroll
        for (int idx = t; idx < K * 16; idx += 256) ws4[idx] = w4[idx];
    }
    {   // stage x tile (padded rows)
        const float4* in4 = (const float4*)(in + (size_t)row0 * K);
        int total4 = nrows * (K / 4);
        for (int idx = t; idx < total4; idx += 256) {
            int r = idx / (K / 4), kk = idx - r * (K / 4);
            float4 v = in4[idx];
            *(float4*)&xs[r * XSS + kk * 4] = v;
        }
    }
    __syncthreads();

    int cg = t & 15;           // cols cg*4 .. cg*4+3
    int rg = t >> 4;           // rows rg*4 .. rg*4+3
    float acc[4][4];
#pragma unroll
    for (int r = 0; r < 4; r++)
#pragma unroll
        for (int c = 0; c < 4; c++) acc[r][c] = 0.f;

    const float* xbase = &xs[rg * 4 * XSS];
    const float* wbase = &ws[cg * 4];
#pragma unroll 4
    for (int k = 0; k < K; k += 4) {
        float4 a0 = *(const float4*)&xbase[0 * XSS + k];
        float4 a1 = *(const float4*)&xbase[1 * XSS + k];
        float4 a2 = *(const float4*)&xbase[2 * XSS + k];
        float4 a3 = *(const float4*)&xbase[3 * XSS + k];
        float4 w0 = *(const float4*)&wbase[(k + 0) * 64];
        float4 w1 = *(const float4*)&wbase[(k + 1) * 64];
        float4 w2 = *(const float4*)&wbase[(k + 2) * 64];
        float4 w3 = *(const float4*)&wbase[(k + 3) * 64];
#pragma unroll
        for (int r = 0; r < 4; r++) {
            float4 a = (r == 0) ? a0 : (r == 1) ? a1 : (r == 2) ? a2 : a3;
            acc[r][0] += a.x * w0.x + a.y * w1.x + a.z * w2.x + a.w * w3.x;
            acc[r][1] += a.x * w0.y + a.y * w1.y + a.z * w2.y + a.w * w3.y;
            acc[r][2] += a.x * w0.z + a.y * w1.z + a.z * w2.z + a.w * w3.z;
            acc[r][3] += a.x * w0.w + a.y * w1.w + a.z * w2.w + a.w * w3.w;
        }
    }
#pragma unroll
    for (int r = 0; r < 4; r++) {
        int row = rg * 4 + r;
        if (row < nrows) {
            float4 v = make_float4(acc[r][0], acc[r][1], acc[r][2], acc[r][3]);
            *(float4*)&out[(size_t)(row0 + row) * 64 + cg * 4] = v;
        }
    }
}

// ---------------- aggregation + bias + BN + ReLU ----------------
// one wave (64 lanes = 64 features) per node; edge loop unrolled x4
__global__ __launch_bounds__(256) void agg_kernel(
        const float* __restrict__ hlin, const int* __restrict__ row_start,
        const int2* __restrict__ csr, const float* __restrict__ dinv,
        const float* __restrict__ bias, const float* __restrict__ gam,
        const float* __restrict__ bet, const float* __restrict__ mu,
        const float* __restrict__ var,
        float* __restrict__ out, int n) {
    int i = blockIdx.x * 4 + (threadIdx.x >> 6);
    int lane = threadIdx.x & 63;
    if (i >= n) return;
    float di = dinv[i];
    float acc = di * di * hlin[(size_t)i * 64 + lane];   // self-loop
    int rs = row_start[i], re = row_start[i + 1];
    int j = rs;
    for (; j + 4 <= re; j += 4) {
        int2 e0 = csr[j + 0];
        int2 e1 = csr[j + 1];
        int2 e2 = csr[j + 2];
        int2 e3 = csr[j + 3];
        float h0 = hlin[(size_t)e0.x * 64 + lane];
        float h1 = hlin[(size_t)e1.x * 64 + lane];
        float h2 = hlin[(size_t)e2.x * 64 + lane];
        float h3 = hlin[(size_t)e3.x * 64 + lane];
        acc += __int_as_float(e0.y) * h0;
        acc += __int_as_float(e1.y) * h1;
        acc += __int_as_float(e2.y) * h2;
        acc += __int_as_float(e3.y) * h3;
    }
    for (; j < re; j++) {
        int2 e = csr[j];
        acc += __int_as_float(e.y) * hlin[(size_t)e.x * 64 + lane];
    }
    float scale = gam[lane] * rsqrtf(var[lane] + BN_EPS);
    float r = (acc + bias[lane] - mu[lane]) * scale + bet[lane];
    out[(size_t)i * 64 + lane] = r > 0.f ? r : 0.f;
}

// ---------------- pool (sorted batch) + MLP ----------------
// one block (64 threads) per graph
__global__ void pool_mlp_kernel(const float* __restrict__ h, const int* __restrict__ batch,
                                const float* __restrict__ l1w, const float* __restrict__ l1b,
                                const float* __restrict__ l2w, const float* __restrict__ l2b,
                                float* __restrict__ out, int n) {
    int g = blockIdx.x;
    int lane = threadIdx.x;
    int lo = 0, hi = n;
    while (lo < hi) { int mid = (lo + hi) >> 1; if (batch[mid] < g) lo = mid + 1; else hi = mid; }
    int start = lo;
    lo = start; hi = n;
    while (lo < hi) { int mid = (lo + hi) >> 1; if (batch[mid] < g + 1) lo = mid + 1; else hi = mid; }
    int end = lo;

    float acc = 0.f;
    for (int i = start; i < end; i++) acc += h[(size_t)i * 64 + lane];

    __shared__ float p[64];
    __shared__ float h1[32];
    p[lane] = acc;
    __syncthreads();
    if (lane < 32) {
        float a = l1b[lane];
#pragma unroll 8
        for (int k = 0; k < 64; k++) a += p[k] * l1w[k * 32 + lane];
        h1[lane] = a > 0.f ? a : 0.f;
    }
    __syncthreads();
    if (lane < 2) {
        float a = l2b[lane];
#pragma unroll 8
        for (int j = 0; j < 32; j++) a += h1[j] * l2w[j * 2 + lane];
        out[g * 2 + lane] = a;
    }
}

extern "C" void kernel_launch(void* const* d_in, const int* in_sizes, int n_in,
                              void* d_out, int out_size, void* d_ws, size_t ws_size,
                              hipStream_t stream) {
    const float* x     = (const float*)d_in[0];
    const int*   ei    = (const int*)d_in[1];
    const int*   batch = (const int*)d_in[2];
    const float* w0 = (const float*)d_in[3];
    const float* b0 = (const float*)d_in[4];
    const float* w1 = (const float*)d_in[5];
    const float* b1 = (const float*)d_in[6];
    const float* w2 = (const float*)d_in[7];
    const float* b2 = (const float*)d_in[8];
    const float* g0 = (const float*)d_in[9];
    const float* be0 = (const float*)d_in[10];
    const float* m0 = (const float*)d_in[11];
    const float* v0 = (const float*)d_in[12];
    const float* g1 = (const float*)d_in[13];
    const float* be1 = (const float*)d_in[14];
    const float* m1 = (const float*)d_in[15];
    const float* v1 = (const float*)d_in[16];
    const float* g2 = (const float*)d_in[17];
    const float* be2 = (const float*)d_in[18];
    const float* m2 = (const float*)d_in[19];
    const float* v2 = (const float*)d_in[20];
    const float* l1w = (const float*)d_in[21];
    const float* l1b = (const float*)d_in[22];
    const float* l2w = (const float*)d_in[23];
    const float* l2b = (const float*)d_in[24];
    float* out = (float*)d_out;

    const int N = in_sizes[2];
    const int E = in_sizes[1] / 2;
    const int G = out_size / 2;

    const int* src = ei;
    const int* dst = ei + E;

    // workspace layout
    char* p = (char*)d_ws;
    auto alloc = [&](size_t bytes) -> void* {
        void* r = (void*)p;
        p += (bytes + 255) & ~(size_t)255;
        return r;
    };
    float* dinvp    = (float*)alloc((size_t)N * 4);
    int*   cnt      = (int*)alloc((size_t)N * 4);
    int*   row_start= (int*)alloc((size_t)(N + 1) * 4);
    int*   cursor   = (int*)alloc((size_t)N * 4);
    int    NB       = (N + SCAN_CHUNK - 1) / SCAN_CHUNK;
    int*   bsums    = (int*)alloc((size_t)NB * 4);
    int2*  csr      = (int2*)alloc((size_t)E * 8);
    float* h_a      = (float*)alloc((size_t)N * 64 * 4);
    float* h_b      = (float*)alloc((size_t)N * 64 * 4);
    (void)ws_size;

    // ---- graph preprocessing ----
    hipMemsetAsync(cnt, 0, (size_t)N * 4, stream);
    hist_kernel<<<(E + 255) / 256, 256, 0, stream>>>(dst, cnt, E);
    dinv_kernel<<<(N + 255) / 256, 256, 0, stream>>>(cnt, dinvp, N);
    scan_block_sums<<<NB, 256, 0, stream>>>(cnt, bsums, N);
    scan_exclusive_bsums<<<1, 64, 0, stream>>>(bsums, NB);
    scan_write<<<NB, 256, 0, stream>>>(cnt, bsums, row_start, N, E);
    hipMemsetAsync(cursor, 0, (size_t)N * 4, stream);
    scatter_kernel<<<(E + 255) / 256, 256, 0, stream>>>(src, dst, row_start, cursor, dinvp,
                                                        csr, E);

    const int nblk = (N + 3) / 4;
    const int lblk = (N + 63) / 64;
    // ---- layer 0 ----
    lin2<128><<<lblk, 256, 0, stream>>>(x, w0, h_a, N);
    agg_kernel<<<nblk, 256, 0, stream>>>(h_a, row_start, csr, dinvp,
                                         b0, g0, be0, m0, v0, h_b, N);
    // ---- layer 1 ----
    lin2<64><<<lblk, 256, 0, stream>>>(h_b, w1, h_a, N);
    agg_kernel<<<nblk, 256, 0, stream>>>(h_a, row_start, csr, dinvp,
                                         b1, g1, be1, m1, v1, h_b, N);
    // ---- layer 2 ----
    lin2<64><<<lblk, 256, 0, stream>>>(h_b, w2, h_a, N);
    agg_kernel<<<nblk, 256, 0, stream>>>(h_a, row_start, csr, dinvp,
                                         b2, g2, be2, m2, v2, h_b, N);
    // ---- pool + MLP ----
    pool_mlp_kernel<<<G, 64, 0, stream>>>(h_b, batch, l1w, l1b, l2w, l2b, out, N);
}

// Round 4
// 612.259 us; speedup vs baseline: 1.8749x; 1.1297x over previous
//
#include <hip/hip_runtime.h>
#include <hip/hip_bf16.h>

#define BN_EPS 1e-5f

// ---------------- degree histogram ----------------
__global__ void hist_kernel(const int* __restrict__ dst, int* __restrict__ cnt, int e) {
    int i = blockIdx.x * 256 + threadIdx.x;
    if (i < e) atomicAdd(&cnt[dst[i]], 1);
}

__global__ void dinv_kernel(const int* __restrict__ cnt, float* __restrict__ dinv, int n) {
    int i = blockIdx.x * 256 + threadIdx.x;
    if (i < n) dinv[i] = rsqrtf((float)(cnt[i] + 1));   // deg = indeg + self-loop >= 1
}

// ---------------- exclusive scan (3-pass, chunk = 1024) ----------------
#define SCAN_CHUNK 1024

__global__ void scan_block_sums(const int* __restrict__ cnt, int* __restrict__ bsums, int n) {
    __shared__ int sdata[256];
    int b = blockIdx.x, t = threadIdx.x;
    int base = b * SCAN_CHUNK;
    int s = 0;
    for (int i = t; i < SCAN_CHUNK; i += 256) {
        int idx = base + i;
        if (idx < n) s += cnt[idx];
    }
    sdata[t] = s;
    __syncthreads();
    for (int off = 128; off > 0; off >>= 1) {
        if (t < off) sdata[t] += sdata[t + off];
        __syncthreads();
    }
    if (t == 0) bsums[b] = sdata[0];
}

__global__ void scan_exclusive_bsums(int* __restrict__ bsums, int nb) {
    if (threadIdx.x == 0 && blockIdx.x == 0) {
        int acc = 0;
        for (int i = 0; i < nb; i++) { int v = bsums[i]; bsums[i] = acc; acc += v; }
    }
}

__global__ void scan_write(const int* __restrict__ cnt, const int* __restrict__ bsums,
                           int* __restrict__ row_start, int n, int e_total) {
    __shared__ int sdata[256];
    int b = blockIdx.x, t = threadIdx.x;
    int base = b * SCAN_CHUNK + t * 4;
    int v0 = 0, v1 = 0, v2 = 0, v3 = 0;
    if (base + 0 < n) v0 = cnt[base + 0];
    if (base + 1 < n) v1 = cnt[base + 1];
    if (base + 2 < n) v2 = cnt[base + 2];
    if (base + 3 < n) v3 = cnt[base + 3];
    int tsum = v0 + v1 + v2 + v3;
    sdata[t] = tsum;
    __syncthreads();
    for (int off = 1; off < 256; off <<= 1) {       // inclusive Hillis-Steele
        int x = (t >= off) ? sdata[t - off] : 0;
        __syncthreads();
        sdata[t] += x;
        __syncthreads();
    }
    int excl = sdata[t] - tsum + bsums[b];
    if (base + 0 < n) row_start[base + 0] = excl;
    if (base + 1 < n) row_start[base + 1] = excl + v0;
    if (base + 2 < n) row_start[base + 2] = excl + v0 + v1;
    if (base + 3 < n) row_start[base + 3] = excl + v0 + v1 + v2;
    if (b == 0 && t == 0) row_start[n] = e_total;
}

// ---------------- CSR scatter (packed {src, val}) ----------------
__global__ void scatter_kernel(const int* __restrict__ src, const int* __restrict__ dst,
                               const int* __restrict__ row_start, int* __restrict__ cursor,
                               const float* __restrict__ dinv,
                               int2* __restrict__ csr, int e) {
    int i = blockIdx.x * 256 + threadIdx.x;
    if (i >= e) return;
    int s = src[i], d = dst[i];
    int pos = row_start[d] + atomicAdd(&cursor[d], 1);
    csr[pos] = make_int2(s, __float_as_int(dinv[s] * dinv[d]));
}

// ---------------- dense linear: out[N,64] = in[N,K] @ w[K,64] ----------------
// block = 256 thr, 64-row tile; x-tile + w staged in LDS (coalesced float4);
// each thread owns a 4x4 micro-tile: 64 FMA per 8 ds_read_b128 -> VALU-bound.
template<int K>
__global__ __launch_bounds__(256) void lin2(const float* __restrict__ in,
                                            const float* __restrict__ w,
                                            float* __restrict__ out, int n) {
    constexpr int XSS = K + 4;                  // +4 pad: breaks pow2 bank stride
    __shared__ float xs[64 * XSS];
    __shared__ float ws[K * 64];
    int t = threadIdx.x;
    int row0 = blockIdx.x * 64;
    int nrows = n - row0; if (nrows > 64) nrows = 64;

    {   // stage w (K*16 float4, contiguous)
        const float4* w4 = (const float4*)w;
        float4* ws4 = (float4*)ws;
#pragma unroll
        for (int idx = t; idx < K * 16; idx += 256) ws4[idx] = w4[idx];
    }
    {   // stage x tile (padded rows)
        const float4* in4 = (const float4*)(in + (size_t)row0 * K);
        int total4 = nrows * (K / 4);
        for (int idx = t; idx < total4; idx += 256) {
            int r = idx / (K / 4), kk = idx - r * (K / 4);
            float4 v = in4[idx];
            *(float4*)&xs[r * XSS + kk * 4] = v;
        }
    }
    __syncthreads();

    int cg = t & 15;           // cols cg*4 .. cg*4+3
    int rg = t >> 4;           // rows rg*4 .. rg*4+3
    float acc[4][4];
#pragma unroll
    for (int r = 0; r < 4; r++)
#pragma unroll
        for (int c = 0; c < 4; c++) acc[r][c] = 0.f;

    const float* xbase = &xs[rg * 4 * XSS];
    const float* wbase = &ws[cg * 4];
#pragma unroll 4
    for (int k = 0; k < K; k += 4) {
        float4 a0 = *(const float4*)&xbase[0 * XSS + k];
        float4 a1 = *(const float4*)&xbase[1 * XSS + k];
        float4 a2 = *(const float4*)&xbase[2 * XSS + k];
        float4 a3 = *(const float4*)&xbase[3 * XSS + k];
        float4 w0 = *(const float4*)&wbase[(k + 0) * 64];
        float4 w1 = *(const float4*)&wbase[(k + 1) * 64];
        float4 w2 = *(const float4*)&wbase[(k + 2) * 64];
        float4 w3 = *(const float4*)&wbase[(k + 3) * 64];
#pragma unroll
        for (int r = 0; r < 4; r++) {
            float4 a = (r == 0) ? a0 : (r == 1) ? a1 : (r == 2) ? a2 : a3;
            acc[r][0] += a.x * w0.x + a.y * w1.x + a.z * w2.x + a.w * w3.x;
            acc[r][1] += a.x * w0.y + a.y * w1.y + a.z * w2.y + a.w * w3.y;
            acc[r][2] += a.x * w0.z + a.y * w1.z + a.z * w2.z + a.w * w3.z;
            acc[r][3] += a.x * w0.w + a.y * w1.w + a.z * w2.w + a.w * w3.w;
        }
    }
#pragma unroll
    for (int r = 0; r < 4; r++) {
        int row = rg * 4 + r;
        if (row < nrows) {
            float4 v = make_float4(acc[r][0], acc[r][1], acc[r][2], acc[r][3]);
            *(float4*)&out[(size_t)(row0 + row) * 64 + cg * 4] = v;
        }
    }
}

// ---------------- aggregation + bias + BN + ReLU ----------------
// one wave (64 lanes = 64 features) per node; edge loop unrolled x4
__global__ __launch_bounds__(256) void agg_kernel(
        const float* __restrict__ hlin, const int* __restrict__ row_start,
        const int2* __restrict__ csr, const float* __restrict__ dinv,
        const float* __restrict__ bias, const float* __restrict__ gam,
        const float* __restrict__ bet, const float* __restrict__ mu,
        const float* __restrict__ var,
        float* __restrict__ out, int n) {
    int i = blockIdx.x * 4 + (threadIdx.x >> 6);
    int lane = threadIdx.x & 63;
    if (i >= n) return;
    float di = dinv[i];
    float acc = di * di * hlin[(size_t)i * 64 + lane];   // self-loop
    int rs = row_start[i], re = row_start[i + 1];
    int j = rs;
    for (; j + 4 <= re; j += 4) {
        int2 e0 = csr[j + 0];
        int2 e1 = csr[j + 1];
        int2 e2 = csr[j + 2];
        int2 e3 = csr[j + 3];
        float h0 = hlin[(size_t)e0.x * 64 + lane];
        float h1 = hlin[(size_t)e1.x * 64 + lane];
        float h2 = hlin[(size_t)e2.x * 64 + lane];
        float h3 = hlin[(size_t)e3.x * 64 + lane];
        acc += __int_as_float(e0.y) * h0;
        acc += __int_as_float(e1.y) * h1;
        acc += __int_as_float(e2.y) * h2;
        acc += __int_as_float(e3.y) * h3;
    }
    for (; j < re; j++) {
        int2 e = csr[j];
        acc += __int_as_float(e.y) * hlin[(size_t)e.x * 64 + lane];
    }
    float scale = gam[lane] * rsqrtf(var[lane] + BN_EPS);
    float r = (acc + bias[lane] - mu[lane]) * scale + bet[lane];
    out[(size_t)i * 64 + lane] = r > 0.f ? r : 0.f;
}

// ---------------- pool stage 1: node-parallel segmented sum ----------------
// wave owns 64 contiguous nodes (batch sorted); lane = feature; flush on
// graph-boundary with coalesced 64-lane atomicAdd.
#define POOL_CHUNK 64
__global__ __launch_bounds__(256) void pool_kernel(const float* __restrict__ h,
                                                   const int* __restrict__ batch,
                                                   float* __restrict__ pooled, int n) {
    int wid = blockIdx.x * 4 + (threadIdx.x >> 6);
    int lane = threadIdx.x & 63;
    int start = wid * POOL_CHUNK;
    if (start >= n) return;
    int end = start + POOL_CHUNK; if (end > n) end = n;
    int cur = batch[start];
    float acc = 0.f;
    for (int i = start; i < end; i++) {
        int b = batch[i];                       // wave-uniform broadcast
        if (b != cur) {
            atomicAdd(&pooled[(size_t)cur * 64 + lane], acc);
            acc = 0.f; cur = b;
        }
        acc += h[(size_t)i * 64 + lane];
    }
    atomicAdd(&pooled[(size_t)cur * 64 + lane], acc);
}

// ---------------- pool stage 2: tiny MLP per graph ----------------
__global__ void mlp_kernel(const float* __restrict__ pooled,
                           const float* __restrict__ l1w, const float* __restrict__ l1b,
                           const float* __restrict__ l2w, const float* __restrict__ l2b,
                           float* __restrict__ out) {
    int g = blockIdx.x;
    int lane = threadIdx.x;
    __shared__ float p[64];
    __shared__ float h1[32];
    p[lane] = pooled[(size_t)g * 64 + lane];
    __syncthreads();
    if (lane < 32) {
        float a = l1b[lane];
#pragma unroll 8
        for (int k = 0; k < 64; k++) a += p[k] * l1w[k * 32 + lane];
        h1[lane] = a > 0.f ? a : 0.f;
    }
    __syncthreads();
    if (lane < 2) {
        float a = l2b[lane];
#pragma unroll 8
        for (int j = 0; j < 32; j++) a += h1[j] * l2w[j * 2 + lane];
        out[g * 2 + lane] = a;
    }
}

extern "C" void kernel_launch(void* const* d_in, const int* in_sizes, int n_in,
                              void* d_out, int out_size, void* d_ws, size_t ws_size,
                              hipStream_t stream) {
    const float* x     = (const float*)d_in[0];
    const int*   ei    = (const int*)d_in[1];
    const int*   batch = (const int*)d_in[2];
    const float* w0 = (const float*)d_in[3];
    const float* b0 = (const float*)d_in[4];
    const float* w1 = (const float*)d_in[5];
    const float* b1 = (const float*)d_in[6];
    const float* w2 = (const float*)d_in[7];
    const float* b2 = (const float*)d_in[8];
    const float* g0 = (const float*)d_in[9];
    const float* be0 = (const float*)d_in[10];
    const float* m0 = (const float*)d_in[11];
    const float* v0 = (const float*)d_in[12];
    const float* g1 = (const float*)d_in[13];
    const float* be1 = (const float*)d_in[14];
    const float* m1 = (const float*)d_in[15];
    const float* v1 = (const float*)d_in[16];
    const float* g2 = (const float*)d_in[17];
    const float* be2 = (const float*)d_in[18];
    const float* m2 = (const float*)d_in[19];
    const float* v2 = (const float*)d_in[20];
    const float* l1w = (const float*)d_in[21];
    const float* l1b = (const float*)d_in[22];
    const float* l2w = (const float*)d_in[23];
    const float* l2b = (const float*)d_in[24];
    float* out = (float*)d_out;

    const int N = in_sizes[2];
    const int E = in_sizes[1] / 2;
    const int G = out_size / 2;

    const int* src = ei;
    const int* dst = ei + E;

    // workspace layout
    char* p = (char*)d_ws;
    auto alloc = [&](size_t bytes) -> void* {
        void* r = (void*)p;
        p += (bytes + 255) & ~(size_t)255;
        return r;
    };
    float* dinvp    = (float*)alloc((size_t)N * 4);
    int*   cnt      = (int*)alloc((size_t)N * 4);
    int*   row_start= (int*)alloc((size_t)(N + 1) * 4);
    int*   cursor   = (int*)alloc((size_t)N * 4);
    int    NB       = (N + SCAN_CHUNK - 1) / SCAN_CHUNK;
    int*   bsums    = (int*)alloc((size_t)NB * 4);
    int2*  csr      = (int2*)alloc((size_t)E * 8);
    float* h_a      = (float*)alloc((size_t)N * 64 * 4);
    float* h_b      = (float*)alloc((size_t)N * 64 * 4);
    float* pooled   = (float*)alloc((size_t)G * 64 * 4);
    (void)ws_size;

    // ---- graph preprocessing ----
    hipMemsetAsync(cnt, 0, (size_t)N * 4, stream);
    hipMemsetAsync(pooled, 0, (size_t)G * 64 * 4, stream);
    hist_kernel<<<(E + 255) / 256, 256, 0, stream>>>(dst, cnt, E);
    dinv_kernel<<<(N + 255) / 256, 256, 0, stream>>>(cnt, dinvp, N);
    scan_block_sums<<<NB, 256, 0, stream>>>(cnt, bsums, N);
    scan_exclusive_bsums<<<1, 64, 0, stream>>>(bsums, NB);
    scan_write<<<NB, 256, 0, stream>>>(cnt, bsums, row_start, N, E);
    hipMemsetAsync(cursor, 0, (size_t)N * 4, stream);
    scatter_kernel<<<(E + 255) / 256, 256, 0, stream>>>(src, dst, row_start, cursor, dinvp,
                                                        csr, E);

    const int nblk = (N + 3) / 4;
    const int lblk = (N + 63) / 64;
    // ---- layer 0 ----
    lin2<128><<<lblk, 256, 0, stream>>>(x, w0, h_a, N);
    agg_kernel<<<nblk, 256, 0, stream>>>(h_a, row_start, csr, dinvp,
                                         b0, g0, be0, m0, v0, h_b, N);
    // ---- layer 1 ----
    lin2<64><<<lblk, 256, 0, stream>>>(h_b, w1, h_a, N);
    agg_kernel<<<nblk, 256, 0, stream>>>(h_a, row_start, csr, dinvp,
                                         b1, g1, be1, m1, v1, h_b, N);
    // ---- layer 2 ----
    lin2<64><<<lblk, 256, 0, stream>>>(h_b, w2, h_a, N);
    agg_kernel<<<nblk, 256, 0, stream>>>(h_a, row_start, csr, dinvp,
                                         b2, g2, be2, m2, v2, h_b, N);
    // ---- pool + MLP ----
    const int pwaves = (N + POOL_CHUNK - 1) / POOL_CHUNK;
    pool_kernel<<<(pwaves + 3) / 4, 256, 0, stream>>>(h_b, batch, pooled, N);
    mlp_kernel<<<G, 64, 0, stream>>>(pooled, l1w, l1b, l2w, l2b, out);
}

// Round 5
// 557.732 us; speedup vs baseline: 2.0582x; 1.0978x over previous
//
#include <hip/hip_runtime.h>
#include <hip/hip_bf16.h>

#define BN_EPS 1e-5f

static __device__ __forceinline__ unsigned short f2bf(float f) {
    unsigned u = __float_as_uint(f);
    unsigned r = (u + 0x7FFF + ((u >> 16) & 1)) >> 16;
    return (unsigned short)r;
}
static __device__ __forceinline__ float bf2f(unsigned short s) {
    return __uint_as_float((unsigned)s << 16);
}
__device__ __forceinline__ int pad8i(int c) { return (c + 7) & ~7; }

// ---------------- degree histogram ----------------
__global__ void hist_kernel(const int* __restrict__ dst, int* __restrict__ cnt, int e) {
    int i = blockIdx.x * 256 + threadIdx.x;
    if (i < e) atomicAdd(&cnt[dst[i]], 1);
}

__global__ void dinv_kernel(const int* __restrict__ cnt, float* __restrict__ dinv, int n) {
    int i = blockIdx.x * 256 + threadIdx.x;
    if (i < n) dinv[i] = rsqrtf((float)(cnt[i] + 1));   // deg = indeg + self-loop >= 1
}

// ---------------- exclusive scan over PADDED counts (3-pass, chunk = 1024) ----
#define SCAN_CHUNK 1024

__global__ void scan_block_sums(const int* __restrict__ cnt, int* __restrict__ bsums, int n) {
    __shared__ int sdata[256];
    int b = blockIdx.x, t = threadIdx.x;
    int base = b * SCAN_CHUNK;
    int s = 0;
    for (int i = t; i < SCAN_CHUNK; i += 256) {
        int idx = base + i;
        if (idx < n) s += pad8i(cnt[idx]);
    }
    sdata[t] = s;
    __syncthreads();
    for (int off = 128; off > 0; off >>= 1) {
        if (t < off) sdata[t] += sdata[t + off];
        __syncthreads();
    }
    if (t == 0) bsums[b] = sdata[0];
}

__global__ void scan_exclusive_bsums(int* __restrict__ bsums, int nb) {
    if (threadIdx.x == 0 && blockIdx.x == 0) {
        int acc = 0;
        for (int i = 0; i < nb; i++) { int v = bsums[i]; bsums[i] = acc; acc += v; }
    }
}

__global__ void scan_write(const int* __restrict__ cnt, const int* __restrict__ bsums,
                           int* __restrict__ row_start, int n) {
    __shared__ int sdata[256];
    int b = blockIdx.x, t = threadIdx.x;
    int base = b * SCAN_CHUNK + t * 4;
    int v0 = 0, v1 = 0, v2 = 0, v3 = 0;
    if (base + 0 < n) v0 = pad8i(cnt[base + 0]);
    if (base + 1 < n) v1 = pad8i(cnt[base + 1]);
    if (base + 2 < n) v2 = pad8i(cnt[base + 2]);
    if (base + 3 < n) v3 = pad8i(cnt[base + 3]);
    int tsum = v0 + v1 + v2 + v3;
    sdata[t] = tsum;
    __syncthreads();
    for (int off = 1; off < 256; off <<= 1) {       // inclusive Hillis-Steele
        int x = (t >= off) ? sdata[t - off] : 0;
        __syncthreads();
        sdata[t] += x;
        __syncthreads();
    }
    int excl = sdata[t] - tsum + bsums[b];
    if (base + 0 < n) row_start[base + 0] = excl;
    if (base + 1 < n) row_start[base + 1] = excl + v0;
    if (base + 2 < n) row_start[base + 2] = excl + v0 + v1;
    if (base + 3 < n) row_start[base + 3] = excl + v0 + v1 + v2;
    if (n - 1 >= base && n - 1 < base + 4)          // finalize total (padded end)
        row_start[n] = excl + v0 + v1 + v2 + v3;
}

// ---------------- CSR scatter (packed {src, val}; pads stay zero) ----------
__global__ void scatter_kernel(const int* __restrict__ src, const int* __restrict__ dst,
                               const int* __restrict__ row_start, int* __restrict__ cursor,
                               const float* __restrict__ dinv,
                               int2* __restrict__ csr, int e) {
    int i = blockIdx.x * 256 + threadIdx.x;
    if (i >= e) return;
    int s = src[i], d = dst[i];
    int pos = row_start[d] + atomicAdd(&cursor[d], 1);
    csr[pos] = make_int2(s, __float_as_int(dinv[s] * dinv[d]));
}

// ---------------- dense linear: outbf[N,64] = in[N,K] @ w[K,64] (bf16 out) --
// block = 256 thr, 64-row tile; x-tile + w staged in LDS (coalesced float4);
// each thread owns a 4x4 micro-tile: 64 FMA per 8 ds_read_b128 -> VALU-bound.
template<int K>
__global__ __launch_bounds__(256) void lin2(const float* __restrict__ in,
                                            const float* __restrict__ w,
                                            unsigned short* __restrict__ outbf, int n) {
    constexpr int XSS = K + 4;                  // +4 pad: breaks pow2 bank stride
    __shared__ float xs[64 * XSS];
    __shared__ float ws[K * 64];
    int t = threadIdx.x;
    int row0 = blockIdx.x * 64;
    int nrows = n - row0; if (nrows > 64) nrows = 64;

    {   // stage w (K*16 float4, contiguous)
        const float4* w4 = (const float4*)w;
        float4* ws4 = (float4*)ws;
#pragma unroll
        for (int idx = t; idx < K * 16; idx += 256) ws4[idx] = w4[idx];
    }
    {   // stage x tile (padded rows)
        const float4* in4 = (const float4*)(in + (size_t)row0 * K);
        int total4 = nrows * (K / 4);
        for (int idx = t; idx < total4; idx += 256) {
            int r = idx / (K / 4), kk = idx - r * (K / 4);
            float4 v = in4[idx];
            *(float4*)&xs[r * XSS + kk * 4] = v;
        }
    }
    __syncthreads();

    int cg = t & 15;           // cols cg*4 .. cg*4+3
    int rg = t >> 4;           // rows rg*4 .. rg*4+3
    float acc[4][4];
#pragma unroll
    for (int r = 0; r < 4; r++)
#pragma unroll
        for (int c = 0; c < 4; c++) acc[r][c] = 0.f;

    const float* xbase = &xs[rg * 4 * XSS];
    const float* wbase = &ws[cg * 4];
#pragma unroll 4
    for (int k = 0; k < K; k += 4) {
        float4 a0 = *(const float4*)&xbase[0 * XSS + k];
        float4 a1 = *(const float4*)&xbase[1 * XSS + k];
        float4 a2 = *(const float4*)&xbase[2 * XSS + k];
        float4 a3 = *(const float4*)&xbase[3 * XSS + k];
        float4 w0 = *(const float4*)&wbase[(k + 0) * 64];
        float4 w1 = *(const float4*)&wbase[(k + 1) * 64];
        float4 w2 = *(const float4*)&wbase[(k + 2) * 64];
        float4 w3 = *(const float4*)&wbase[(k + 3) * 64];
#pragma unroll
        for (int r = 0; r < 4; r++) {
            float4 a = (r == 0) ? a0 : (r == 1) ? a1 : (r == 2) ? a2 : a3;
            acc[r][0] += a.x * w0.x + a.y * w1.x + a.z * w2.x + a.w * w3.x;
            acc[r][1] += a.x * w0.y + a.y * w1.y + a.z * w2.y + a.w * w3.y;
            acc[r][2] += a.x * w0.z + a.y * w1.z + a.z * w2.z + a.w * w3.z;
            acc[r][3] += a.x * w0.w + a.y * w1.w + a.z * w2.w + a.w * w3.w;
        }
    }
#pragma unroll
    for (int r = 0; r < 4; r++) {
        int row = rg * 4 + r;
        if (row < nrows) {
            ushort4 v;
            v.x = f2bf(acc[r][0]); v.y = f2bf(acc[r][1]);
            v.z = f2bf(acc[r][2]); v.w = f2bf(acc[r][3]);
            *(ushort4*)&outbf[(size_t)(row0 + row) * 64 + cg * 4] = v;
        }
    }
}

// ---------------- aggregation + bias + BN + ReLU (bf16 gather, unroll 8) ----
__global__ __launch_bounds__(256) void agg_kernel(
        const unsigned short* __restrict__ hlin, const int* __restrict__ row_start,
        const int2* __restrict__ csr, const float* __restrict__ dinv,
        const float* __restrict__ bias, const float* __restrict__ gam,
        const float* __restrict__ bet, const float* __restrict__ mu,
        const float* __restrict__ var,
        float* __restrict__ out, int n) {
    int i = blockIdx.x * 4 + (threadIdx.x >> 6);
    int lane = threadIdx.x & 63;
    if (i >= n) return;
    float di = dinv[i];
    float acc = di * di * bf2f(hlin[(size_t)i * 64 + lane]);   // self-loop
    int rs = row_start[i], re = row_start[i + 1];              // padded to x8
    for (int j = rs; j < re; j += 8) {
        int2 e0 = csr[j + 0];
        int2 e1 = csr[j + 1];
        int2 e2 = csr[j + 2];
        int2 e3 = csr[j + 3];
        int2 e4 = csr[j + 4];
        int2 e5 = csr[j + 5];
        int2 e6 = csr[j + 6];
        int2 e7 = csr[j + 7];
        float h0 = bf2f(hlin[(size_t)e0.x * 64 + lane]);
        float h1 = bf2f(hlin[(size_t)e1.x * 64 + lane]);
        float h2 = bf2f(hlin[(size_t)e2.x * 64 + lane]);
        float h3 = bf2f(hlin[(size_t)e3.x * 64 + lane]);
        float h4 = bf2f(hlin[(size_t)e4.x * 64 + lane]);
        float h5 = bf2f(hlin[(size_t)e5.x * 64 + lane]);
        float h6 = bf2f(hlin[(size_t)e6.x * 64 + lane]);
        float h7 = bf2f(hlin[(size_t)e7.x * 64 + lane]);
        acc += __int_as_float(e0.y) * h0;
        acc += __int_as_float(e1.y) * h1;
        acc += __int_as_float(e2.y) * h2;
        acc += __int_as_float(e3.y) * h3;
        acc += __int_as_float(e4.y) * h4;
        acc += __int_as_float(e5.y) * h5;
        acc += __int_as_float(e6.y) * h6;
        acc += __int_as_float(e7.y) * h7;
    }
    float scale = gam[lane] * rsqrtf(var[lane] + BN_EPS);
    float r = (acc + bias[lane] - mu[lane]) * scale + bet[lane];
    out[(size_t)i * 64 + lane] = r > 0.f ? r : 0.f;
}

// ---------------- pool stage 1: node-parallel segmented sum ----------------
#define POOL_CHUNK 64
__global__ __launch_bounds__(256) void pool_kernel(const float* __restrict__ h,
                                                   const int* __restrict__ batch,
                                                   float* __restrict__ pooled, int n) {
    int wid = blockIdx.x * 4 + (threadIdx.x >> 6);
    int lane = threadIdx.x & 63;
    int start = wid * POOL_CHUNK;
    if (start >= n) return;
    int end = start + POOL_CHUNK; if (end > n) end = n;
    int cur = batch[start];
    float acc = 0.f;
    for (int i = start; i < end; i++) {
        int b = batch[i];                       // wave-uniform broadcast
        if (b != cur) {
            atomicAdd(&pooled[(size_t)cur * 64 + lane], acc);
            acc = 0.f; cur = b;
        }
        acc += h[(size_t)i * 64 + lane];
    }
    atomicAdd(&pooled[(size_t)cur * 64 + lane], acc);
}

// ---------------- pool stage 2: tiny MLP per graph ----------------
__global__ void mlp_kernel(const float* __restrict__ pooled,
                           const float* __restrict__ l1w, const float* __restrict__ l1b,
                           const float* __restrict__ l2w, const float* __restrict__ l2b,
                           float* __restrict__ out) {
    int g = blockIdx.x;
    int lane = threadIdx.x;
    __shared__ float p[64];
    __shared__ float h1[32];
    p[lane] = pooled[(size_t)g * 64 + lane];
    __syncthreads();
    if (lane < 32) {
        float a = l1b[lane];
#pragma unroll 8
        for (int k = 0; k < 64; k++) a += p[k] * l1w[k * 32 + lane];
        h1[lane] = a > 0.f ? a : 0.f;
    }
    __syncthreads();
    if (lane < 2) {
        float a = l2b[lane];
#pragma unroll 8
        for (int j = 0; j < 32; j++) a += h1[j] * l2w[j * 2 + lane];
        out[g * 2 + lane] = a;
    }
}

extern "C" void kernel_launch(void* const* d_in, const int* in_sizes, int n_in,
                              void* d_out, int out_size, void* d_ws, size_t ws_size,
                              hipStream_t stream) {
    const float* x     = (const float*)d_in[0];
    const int*   ei    = (const int*)d_in[1];
    const int*   batch = (const int*)d_in[2];
    const float* w0 = (const float*)d_in[3];
    const float* b0 = (const float*)d_in[4];
    const float* w1 = (const float*)d_in[5];
    const float* b1 = (const float*)d_in[6];
    const float* w2 = (const float*)d_in[7];
    const float* b2 = (const float*)d_in[8];
    const float* g0 = (const float*)d_in[9];
    const float* be0 = (const float*)d_in[10];
    const float* m0 = (const float*)d_in[11];
    const float* v0 = (const float*)d_in[12];
    const float* g1 = (const float*)d_in[13];
    const float* be1 = (const float*)d_in[14];
    const float* m1 = (const float*)d_in[15];
    const float* v1 = (const float*)d_in[16];
    const float* g2 = (const float*)d_in[17];
    const float* be2 = (const float*)d_in[18];
    const float* m2 = (const float*)d_in[19];
    const float* v2 = (const float*)d_in[20];
    const float* l1w = (const float*)d_in[21];
    const float* l1b = (const float*)d_in[22];
    const float* l2w = (const float*)d_in[23];
    const float* l2b = (const float*)d_in[24];
    float* out = (float*)d_out;

    const int N = in_sizes[2];
    const int E = in_sizes[1] / 2;
    const int G = out_size / 2;

    const int* src = ei;
    const int* dst = ei + E;

    // workspace layout
    char* p = (char*)d_ws;
    auto alloc = [&](size_t bytes) -> void* {
        void* r = (void*)p;
        p += (bytes + 255) & ~(size_t)255;
        return r;
    };
    const size_t CSR_CAP = (size_t)E + 8 * (size_t)N;   // padded capacity
    float* dinvp    = (float*)alloc((size_t)N * 4);
    int*   cnt      = (int*)alloc((size_t)N * 4);
    int*   row_start= (int*)alloc((size_t)(N + 1) * 4);
    int*   cursor   = (int*)alloc((size_t)N * 4);
    int    NB       = (N + SCAN_CHUNK - 1) / SCAN_CHUNK;
    int*   bsums    = (int*)alloc((size_t)NB * 4);
    int2*  csr      = (int2*)alloc(CSR_CAP * 8);
    unsigned short* h_a = (unsigned short*)alloc((size_t)N * 64 * 2);  // bf16 lin out
    float* h_b      = (float*)alloc((size_t)N * 64 * 4);               // fp32 agg out
    float* pooled   = (float*)alloc((size_t)G * 64 * 4);
    (void)ws_size;

    // ---- graph preprocessing ----
    hipMemsetAsync(cnt, 0, (size_t)N * 4, stream);
    hipMemsetAsync(pooled, 0, (size_t)G * 64 * 4, stream);
    hipMemsetAsync(csr, 0, CSR_CAP * 8, stream);        // pads -> {src=0, val=0}
    hist_kernel<<<(E + 255) / 256, 256, 0, stream>>>(dst, cnt, E);
    dinv_kernel<<<(N + 255) / 256, 256, 0, stream>>>(cnt, dinvp, N);
    scan_block_sums<<<NB, 256, 0, stream>>>(cnt, bsums, N);
    scan_exclusive_bsums<<<1, 64, 0, stream>>>(bsums, NB);
    scan_write<<<NB, 256, 0, stream>>>(cnt, bsums, row_start, N);
    hipMemsetAsync(cursor, 0, (size_t)N * 4, stream);
    scatter_kernel<<<(E + 255) / 256, 256, 0, stream>>>(src, dst, row_start, cursor, dinvp,
                                                        csr, E);

    const int nblk = (N + 3) / 4;
    const int lblk = (N + 63) / 64;
    // ---- layer 0 ----
    lin2<128><<<lblk, 256, 0, stream>>>(x, w0, h_a, N);
    agg_kernel<<<nblk, 256, 0, stream>>>(h_a, row_start, csr, dinvp,
                                         b0, g0, be0, m0, v0, h_b, N);
    // ---- layer 1 ----
    lin2<64><<<lblk, 256, 0, stream>>>(h_b, w1, h_a, N);
    agg_kernel<<<nblk, 256, 0, stream>>>(h_a, row_start, csr, dinvp,
                                         b1, g1, be1, m1, v1, h_b, N);
    // ---- layer 2 ----
    lin2<64><<<lblk, 256, 0, stream>>>(h_b, w2, h_a, N);
    agg_kernel<<<nblk, 256, 0, stream>>>(h_a, row_start, csr, dinvp,
                                         b2, g2, be2, m2, v2, h_b, N);
    // ---- pool + MLP ----
    const int pwaves = (N + POOL_CHUNK - 1) / POOL_CHUNK;
    pool_kernel<<<(pwaves + 3) / 4, 256, 0, stream>>>(h_b, batch, pooled, N);
    mlp_kernel<<<G, 64, 0, stream>>>(pooled, l1w, l1b, l2w, l2b, out);
}